// Round 7
// baseline (766.297 us; speedup 1.0000x reference)
//
#include <hip/hip_runtime.h>

// SpecAdaConv2d via split-bf16 MFMA implicit GEMM.
// out[b,co,p] = sum_{ci,k} (alpha[b,ci]*w[co,ci,k]) * x[b,ci,p+shift(k)] + bias[co]
// fp32 -> (hi,lo) bf16 split on both w and x; 3 products hi*hi + hi*lo_x + lo_w*hi.
//
// R7 = R5 (XCD swizzle + T14 pipeline, 175us best) with the pipeline deepened:
// persistent 4-tile blocks. Grid 512 (= 2 blocks/CU, all resident whole
// kernel); each block sweeps 4 x-adjacent tiles of one batch image, 8
// (tile,chunk) pairs; 7/8 staging loads issue under the previous pair's MFMA,
// epilogues interleave at tile boundaries (stores overlap next compute).
// R6's swizzled-LDS REVERTED (measured: -read-conflicts bought 0, occupancy
// unmoved, +55% L2 traffic, 175->230us). LDS bank effects here are all
// latency-hidden; RS=72 layout is final.

typedef __attribute__((ext_vector_type(8))) short short8;
typedef __attribute__((ext_vector_type(4))) float float4v;

#define BB 8
#define CI_N 64
#define CO_N 64
#define HH 256
#define WW 256
#define HW (HH * WW)
#define TW 32
#define TH 8
#define HALO_W 34
#define HALO_H 10
#define HALO_PX (HALO_W * HALO_H)   // 340
#define RS 72                        // packed row: [32 hi][32 lo][8 pad] ushorts
#define HI_OFF 32                    // lo block starts 32 ushorts (64 B) into row

#define NFRAG (2 * 9 * 2 * 4 * 64 * 8)  // 73728 packed bf16 elems

__device__ __forceinline__ unsigned f2bf(float v) {
    unsigned u = __float_as_uint(v);
    return (u + 0x7FFFu + ((u >> 16) & 1u)) >> 16;   // RNE to bf16
}

__global__ void prepack_w(const float* __restrict__ w, ushort* __restrict__ wp) {
    int idx = blockIdx.x * 256 + threadIdx.x;
    if (idx >= NFRAG) return;
    int j     = idx & 7;
    int lane  = (idx >> 3) & 63;
    int mt    = (idx >> 9) & 3;
    int plane = (idx >> 11) & 1;
    int rest  = idx >> 12;            // chunk*9 + k, 0..17
    int k     = rest % 9;
    int chunk = rest / 9;
    int co = mt * 16 + (lane & 15);
    int ci = chunk * 32 + (lane >> 4) * 8 + j;
    float v = w[(co * CI_N + ci) * 9 + k];
    unsigned hi = f2bf(v);
    float fhi = __uint_as_float(hi << 16);
    unsigned lo = f2bf(v - fhi);
    wp[idx] = (ushort)(plane ? lo : hi);
}

__global__ __launch_bounds__(512, 4) void conv_mfma(
    const float* __restrict__ x,      // (B, CIN, H, W)
    const float* __restrict__ alpha,  // (B, CIN)
    const ushort* __restrict__ wp,    // packed weights (d_ws)
    const float* __restrict__ bias,   // (COUT)
    float* __restrict__ out)          // (B, COUT, H, W)
{
    __shared__ __align__(16) ushort sx[HALO_PX * RS];

    const int tid    = threadIdx.x;
    const int lane   = tid & 63;
    const int w_id   = tid >> 6;        // wave 0..7
    const int n_lane = lane & 15;
    const int q      = lane >> 4;

    // XCD-aware decode: id&7 pins one batch per XCD; each block owns 4
    // x-adjacent tiles (ty, txq*4 .. txq*4+3) of that image.
    const int id  = blockIdx.x;         // 0..511
    const int b   = id & 7;
    const int s   = id >> 3;            // 0..63
    const int ty  = s >> 1;             // 0..31
    const int txq = s & 1;              // tile-quad: tx = txq*4 + ti
    const int gy0 = ty * TH;

    const int m_half = w_id >> 2;       // owns M-tiles m_half*2 + {0,1}
    const int n_q    = w_id & 3;        // owns N-tiles n_q*4 + {0..3}

    // bias fragment kept resident for per-tile acc reinit
    float4v bi2[2];
#pragma unroll
    for (int mt = 0; mt < 2; ++mt)
#pragma unroll
        for (int r = 0; r < 4; ++r)
            bi2[mt][r] = bias[(m_half * 2 + mt) * 16 + q * 4 + r];

    float4v acc[2][4];
#pragma unroll
    for (int mt = 0; mt < 2; ++mt)
#pragma unroll
        for (int nt = 0; nt < 4; ++nt) acc[mt][nt] = bi2[mt];

    const float* xb = x + (size_t)b * CI_N * HW;
    // per-lane LDS base for B-frag reads (ushort units): folds n_q rows, n_lane, q
    const int vbase = (n_q * 2 * HALO_W + n_lane) * RS + q * 8;

    const int cl = w_id * 4;   // this wave stages ci = chunk*32 + cl .. +3
    float al0[4], al1[4];      // wave-uniform alphas per chunk
#pragma unroll
    for (int j = 0; j < 4; ++j) {
        al0[j] = alpha[b * CI_N + cl + j];
        al1[j] = alpha[b * CI_N + 32 + cl + j];
    }

    // staging geometry for the tile at gx0 (recomputed per tile)
    int gofs[6];
    unsigned okm;
#define CALC_GOFS(gx0_)                                                  \
    {                                                                    \
        okm = 0;                                                         \
        _Pragma("unroll")                                                \
        for (int it = 0; it < 6; ++it) {                                 \
            int hp = it * 64 + lane;                                     \
            int hy = hp / HALO_W;                                        \
            int hx = hp - hy * HALO_W;                                   \
            int gy = gy0 - 1 + hy;                                       \
            int gx = (gx0_)-1 + hx;                                      \
            bool ok = (hp < HALO_PX) & ((unsigned)gy < HH)               \
                    & ((unsigned)gx < WW);                               \
            gofs[it] = ok ? gy * WW + gx : 0;                            \
            okm |= (unsigned)ok << it;                                   \
        }                                                                \
    }

#define STAGE_LOAD(r, cbase)                                             \
    {                                                                    \
        _Pragma("unroll")                                                \
        for (int j = 0; j < 4; ++j) {                                    \
            const float* xp = xb + (size_t)((cbase) + cl + j) * HW;      \
            _Pragma("unroll")                                            \
            for (int it = 0; it < 6; ++it) r[j][it] = xp[gofs[it]];      \
        }                                                                \
    }

#define STAGE_WRITE(r, al)                                               \
    {                                                                    \
        _Pragma("unroll")                                                \
        for (int it = 0; it < 6; ++it) {                                 \
            if (it < 5 || lane < 20) {  /* unit exists (hp<340) */       \
                const int hp = it * 64 + lane;                           \
                const bool ok = (okm >> it) & 1;                         \
                float v[4];                                              \
                _Pragma("unroll")                                        \
                for (int j = 0; j < 4; ++j)                              \
                    v[j] = ok ? r[j][it] * al[j] : 0.0f;                 \
                _Pragma("unroll")                                        \
                for (int p2 = 0; p2 < 2; ++p2) {                         \
                    unsigned h0 = f2bf(v[2 * p2]);                       \
                    unsigned h1 = f2bf(v[2 * p2 + 1]);                   \
                    unsigned l0 = f2bf(v[2 * p2]                         \
                                       - __uint_as_float(h0 << 16));     \
                    unsigned l1 = f2bf(v[2 * p2 + 1]                     \
                                       - __uint_as_float(h1 << 16));     \
                    *(unsigned*)&sx[hp * RS + cl + 2 * p2] =             \
                        h0 | (h1 << 16);                                 \
                    *(unsigned*)&sx[hp * RS + HI_OFF + cl + 2 * p2] =    \
                        l0 | (l1 << 16);                                 \
                }                                                        \
            }                                                            \
        }                                                                \
    }

#define COMPUTE(chunk)                                                   \
    {                                                                    \
        _Pragma("unroll")                                                \
        for (int k = 0; k < 9; ++k) {                                    \
            const int dy = k / 3 - 1;                                    \
            const int dx = k % 3 - 1;                                    \
            short8 a_hi[2], a_lo[2];                                     \
            _Pragma("unroll")                                            \
            for (int mt = 0; mt < 2; ++mt) {                             \
                int fh = (((chunk) * 9 + k) * 2 + 0) * 4 + (m_half * 2 + mt); \
                int fl = (((chunk) * 9 + k) * 2 + 1) * 4 + (m_half * 2 + mt); \
                a_hi[mt] = *(const short8*)(wp + (size_t)(fh * 64 + lane) * 8); \
                a_lo[mt] = *(const short8*)(wp + (size_t)(fl * 64 + lane) * 8); \
            }                                                            \
            _Pragma("unroll")                                            \
            for (int nt_i = 0; nt_i < 4; ++nt_i) {                       \
                const int off = ((nt_i >> 1) + 1 + dy) * HALO_W + 1      \
                              + (nt_i & 1) * 16 + dx;                    \
                const ushort* bp = &sx[vbase + off * RS];                \
                short8 b_hi = *(const short8*)bp;                        \
                short8 b_lo = *(const short8*)(bp + HI_OFF);             \
                acc[0][nt_i] = __builtin_amdgcn_mfma_f32_16x16x32_bf16(a_hi[0], b_hi, acc[0][nt_i], 0, 0, 0); \
                acc[1][nt_i] = __builtin_amdgcn_mfma_f32_16x16x32_bf16(a_hi[1], b_hi, acc[1][nt_i], 0, 0, 0); \
                acc[0][nt_i] = __builtin_amdgcn_mfma_f32_16x16x32_bf16(a_lo[0], b_hi, acc[0][nt_i], 0, 0, 0); \
                acc[1][nt_i] = __builtin_amdgcn_mfma_f32_16x16x32_bf16(a_lo[1], b_hi, acc[1][nt_i], 0, 0, 0); \
                acc[0][nt_i] = __builtin_amdgcn_mfma_f32_16x16x32_bf16(a_hi[0], b_lo, acc[0][nt_i], 0, 0, 0); \
                acc[1][nt_i] = __builtin_amdgcn_mfma_f32_16x16x32_bf16(a_hi[1], b_lo, acc[1][nt_i], 0, 0, 0); \
            }                                                            \
        }                                                                \
    }

    // ---- persistent 4-tile pipelined schedule ----
    int gx0 = txq * 4 * TW;     // tile 0 of this block's quad
    float r[4][6];
    CALC_GOFS(gx0);
    STAGE_LOAD(r, 0);           // tile0 chunk0 (only fully-exposed load)
    STAGE_WRITE(r, al0);
    __syncthreads();

#pragma unroll 1
    for (int ti = 0; ti < 4; ++ti) {
        STAGE_LOAD(r, 32);      // this tile's chunk1, hides under COMPUTE(0)
        COMPUTE(0);
        __syncthreads();        // sx reads of chunk0 done
        STAGE_WRITE(r, al1);
        __syncthreads();

        const int egx0 = gx0;   // epilogue coords of the CURRENT tile
        if (ti < 3) {           // next tile's chunk0, hides under COMPUTE(1)
            gx0 += TW;
            CALC_GOFS(gx0);
            STAGE_LOAD(r, 0);
        }
        COMPUTE(1);

        // epilogue: store this tile, reinit acc (stores overlap next phases)
#pragma unroll
        for (int mt = 0; mt < 2; ++mt) {
            const int m0 = (m_half * 2 + mt) * 16;
#pragma unroll
            for (int nt_i = 0; nt_i < 4; ++nt_i) {
                const int nt = n_q * 4 + nt_i;
                const int gy = gy0 + (nt >> 1);
                const int gx = egx0 + (nt & 1) * 16 + n_lane;
#pragma unroll
                for (int rr = 0; rr < 4; ++rr) {
                    const int co = m0 + q * 4 + rr;
                    out[(((size_t)b * CO_N + co) * HH + gy) * WW + gx] = acc[mt][nt_i][rr];
                }
                acc[mt][nt_i] = bi2[mt];
            }
        }
        __syncthreads();        // sx reads of chunk1 done
        if (ti < 3) {
            STAGE_WRITE(r, al0);
            __syncthreads();
        }
    }
#undef CALC_GOFS
#undef STAGE_LOAD
#undef STAGE_WRITE
#undef COMPUTE
}

extern "C" void kernel_launch(void* const* d_in, const int* in_sizes, int n_in,
                              void* d_out, int out_size, void* d_ws, size_t ws_size,
                              hipStream_t stream) {
    const float* x     = (const float*)d_in[0];
    const float* alpha = (const float*)d_in[1];
    const float* w     = (const float*)d_in[2];
    const float* bias  = (const float*)d_in[3];
    float* out  = (float*)d_out;
    ushort* wpk = (ushort*)d_ws;

    prepack_w<<<dim3((NFRAG + 255) / 256), dim3(256), 0, stream>>>(w, wpk);

    // 512 persistent blocks = 2/CU, all resident; 4 tiles each
    conv_mfma<<<dim3(512), dim3(512), 0, stream>>>(x, alpha, wpk, bias, out);
}

// Round 9
// 332.607 us; speedup vs baseline: 2.3039x; 2.3039x over previous
//
#include <hip/hip_runtime.h>

// SpecAdaConv2d via split-bf16 MFMA implicit GEMM.
// out[b,co,p] = sum_{ci,k} (alpha[b,ci]*w[co,ci,k]) * x[b,ci,p+shift(k)] + bias[co]
// fp32 -> (hi,lo) bf16 split on both w and x; 3 products hi*hi + hi*lo_x + lo_w*hi.
//
// R8 (resubmit; prior run died to container infra, no kernel data) =
// R5 (XCD swizzle + T14 pipeline, 175us best) with TH 8->4 so the LDS
// halo tile (204 px x 72 us = 29.4KB) DOUBLE-BUFFERS in 58.8KB (2 blocks/CU =
// R5's measured residency). Schedule per block:
//   load c0; write c0->A; bar;  load c1; COMPUTE(c0,A); write c1->B; bar;
//   COMPUTE(c1,B); store
// -> 2 barriers (was 3), and the c1 LDS-write no longer serializes against
// c0's reads (different buffer). Staging regs shrink to r[4][4]; acc to 16.
// R7 lesson (2nd spill): never extend staging-reg lifetime across a store
// phase inside a loop — this schedule keeps R5's straight-line lifetimes.

typedef __attribute__((ext_vector_type(8))) short short8;
typedef __attribute__((ext_vector_type(4))) float float4v;

#define BB 8
#define CI_N 64
#define CO_N 64
#define HH 256
#define WW 256
#define HW (HH * WW)
#define TW 32
#define TH 4
#define HALO_W 34
#define HALO_H 6
#define HALO_PX (HALO_W * HALO_H)   // 204
#define RS 72                        // packed row: [32 hi][32 lo][8 pad] ushorts
#define HI_OFF 32                    // lo block starts 32 ushorts (64 B) into row

#define NFRAG (2 * 9 * 2 * 4 * 64 * 8)  // 73728 packed bf16 elems

__device__ __forceinline__ unsigned f2bf(float v) {
    unsigned u = __float_as_uint(v);
    return (u + 0x7FFFu + ((u >> 16) & 1u)) >> 16;   // RNE to bf16
}

__global__ void prepack_w(const float* __restrict__ w, ushort* __restrict__ wp) {
    int idx = blockIdx.x * 256 + threadIdx.x;
    if (idx >= NFRAG) return;
    int j     = idx & 7;
    int lane  = (idx >> 3) & 63;
    int mt    = (idx >> 9) & 3;
    int plane = (idx >> 11) & 1;
    int rest  = idx >> 12;            // chunk*9 + k, 0..17
    int k     = rest % 9;
    int chunk = rest / 9;
    int co = mt * 16 + (lane & 15);
    int ci = chunk * 32 + (lane >> 4) * 8 + j;
    float v = w[(co * CI_N + ci) * 9 + k];
    unsigned hi = f2bf(v);
    float fhi = __uint_as_float(hi << 16);
    unsigned lo = f2bf(v - fhi);
    wp[idx] = (ushort)(plane ? lo : hi);
}

__global__ __launch_bounds__(512, 4) void conv_mfma(
    const float* __restrict__ x,      // (B, CIN, H, W)
    const float* __restrict__ alpha,  // (B, CIN)
    const ushort* __restrict__ wp,    // packed weights (d_ws)
    const float* __restrict__ bias,   // (COUT)
    float* __restrict__ out)          // (B, COUT, H, W)
{
    __shared__ __align__(16) ushort sxA[HALO_PX * RS];   // 29376 B
    __shared__ __align__(16) ushort sxB[HALO_PX * RS];   // 29376 B

    const int tid    = threadIdx.x;
    const int lane   = tid & 63;
    const int w_id   = tid >> 6;        // wave 0..7
    const int n_lane = lane & 15;
    const int q      = lane >> 4;

    // XCD-aware decode: id&7 pins one batch image per XCD (proven in R4).
    const int id  = blockIdx.x;         // 0..4095
    const int b   = id & 7;
    const int t   = id >> 3;            // 0..511
    const int tx  = t & 7;
    const int ty  = t >> 3;             // 0..63
    const int gx0 = tx * TW;
    const int gy0 = ty * TH;

    const int m_half = w_id >> 2;       // owns M-tiles m_half*2 + {0,1}
    const int n_q    = w_id & 3;        // owns tile-row n_q (of 4), both halves

    // acc init = bias (C/D layout: col=lane&15 -> px, row=q*4+r -> co)
    float4v acc[2][2];
#pragma unroll
    for (int mt = 0; mt < 2; ++mt) {
        float4v bi;
#pragma unroll
        for (int r = 0; r < 4; ++r)
            bi[r] = bias[(m_half * 2 + mt) * 16 + q * 4 + r];
#pragma unroll
        for (int h = 0; h < 2; ++h) acc[mt][h] = bi;
    }

    const float* xb = x + (size_t)b * CI_N * HW;
    // per-lane LDS base for B-frag reads (ushort units)
    const int vbase = n_lane * RS + q * 8;

    // ---- staging geometry, computed once (shared by both chunks) ----
    int gofs[4];
    unsigned okm = 0;
#pragma unroll
    for (int it = 0; it < 4; ++it) {
        int hp = it * 64 + lane;
        int hy = hp / HALO_W;
        int hx = hp - hy * HALO_W;
        int gy = gy0 - 1 + hy;
        int gx = gx0 - 1 + hx;
        bool ok = (hp < HALO_PX) & ((unsigned)gy < HH) & ((unsigned)gx < WW);
        gofs[it] = ok ? gy * WW + gx : 0;   // clamped: load always valid
        okm |= (unsigned)ok << it;
    }
    const int cl = w_id * 4;   // this wave stages ci = chunk*32 + cl .. +3
    float al0[4], al1[4];      // wave-uniform alphas per chunk
#pragma unroll
    for (int j = 0; j < 4; ++j) {
        al0[j] = alpha[b * CI_N + cl + j];
        al1[j] = alpha[b * CI_N + 32 + cl + j];
    }

    // raw staging loads for one chunk: r[j][it], ci = base+j
#define STAGE_LOAD(r, cbase)                                             \
    {                                                                    \
        _Pragma("unroll")                                                \
        for (int j = 0; j < 4; ++j) {                                    \
            const float* xp = xb + (size_t)((cbase) + cl + j) * HW;      \
            _Pragma("unroll")                                            \
            for (int it = 0; it < 4; ++it) r[j][it] = xp[gofs[it]];      \
        }                                                                \
    }

    // convert + LDS write into the given buffer (R1/R5 layout)
#define STAGE_WRITE(buf, r, al)                                          \
    {                                                                    \
        _Pragma("unroll")                                                \
        for (int it = 0; it < 4; ++it) {                                 \
            if (it < 3 || lane < 12) {  /* unit exists (hp<204) */       \
                const int hp = it * 64 + lane;                           \
                const bool ok = (okm >> it) & 1;                         \
                float v[4];                                              \
                _Pragma("unroll")                                        \
                for (int j = 0; j < 4; ++j)                              \
                    v[j] = ok ? r[j][it] * al[j] : 0.0f;                 \
                _Pragma("unroll")                                        \
                for (int p2 = 0; p2 < 2; ++p2) {                         \
                    unsigned h0 = f2bf(v[2 * p2]);                       \
                    unsigned h1 = f2bf(v[2 * p2 + 1]);                   \
                    unsigned l0 = f2bf(v[2 * p2]                         \
                                       - __uint_as_float(h0 << 16));     \
                    unsigned l1 = f2bf(v[2 * p2 + 1]                     \
                                       - __uint_as_float(h1 << 16));     \
                    *(unsigned*)&buf[hp * RS + cl + 2 * p2] =            \
                        h0 | (h1 << 16);                                 \
                    *(unsigned*)&buf[hp * RS + HI_OFF + cl + 2 * p2] =   \
                        l0 | (l1 << 16);                                 \
                }                                                        \
            }                                                            \
        }                                                                \
    }

    // compute phase for one chunk from the given buffer
#define COMPUTE(chunk, buf)                                              \
    {                                                                    \
        _Pragma("unroll")                                                \
        for (int k = 0; k < 9; ++k) {                                    \
            const int dy = k / 3 - 1;                                    \
            const int dx = k % 3 - 1;                                    \
            short8 a_hi[2], a_lo[2];                                     \
            _Pragma("unroll")                                            \
            for (int mt = 0; mt < 2; ++mt) {                             \
                int fh = (((chunk) * 9 + k) * 2 + 0) * 4 + (m_half * 2 + mt); \
                int fl = (((chunk) * 9 + k) * 2 + 1) * 4 + (m_half * 2 + mt); \
                a_hi[mt] = *(const short8*)(wp + (size_t)(fh * 64 + lane) * 8); \
                a_lo[mt] = *(const short8*)(wp + (size_t)(fl * 64 + lane) * 8); \
            }                                                            \
            _Pragma("unroll")                                            \
            for (int h = 0; h < 2; ++h) {                                \
                const int off = (n_q + 1 + dy) * HALO_W + 1 + h * 16 + dx; \
                const ushort* bp = &buf[vbase + off * RS];               \
                short8 b_hi = *(const short8*)bp;                        \
                short8 b_lo = *(const short8*)(bp + HI_OFF);             \
                acc[0][h] = __builtin_amdgcn_mfma_f32_16x16x32_bf16(a_hi[0], b_hi, acc[0][h], 0, 0, 0); \
                acc[1][h] = __builtin_amdgcn_mfma_f32_16x16x32_bf16(a_hi[1], b_hi, acc[1][h], 0, 0, 0); \
                acc[0][h] = __builtin_amdgcn_mfma_f32_16x16x32_bf16(a_lo[0], b_hi, acc[0][h], 0, 0, 0); \
                acc[1][h] = __builtin_amdgcn_mfma_f32_16x16x32_bf16(a_lo[1], b_hi, acc[1][h], 0, 0, 0); \
                acc[0][h] = __builtin_amdgcn_mfma_f32_16x16x32_bf16(a_hi[0], b_lo, acc[0][h], 0, 0, 0); \
                acc[1][h] = __builtin_amdgcn_mfma_f32_16x16x32_bf16(a_hi[1], b_lo, acc[1][h], 0, 0, 0); \
            }                                                            \
        }                                                                \
    }

    // ---- double-buffered schedule: 2 barriers per block ----
    float r0[4][4], r1[4][4];
    STAGE_LOAD(r0, 0);          // chunk0 loads
    STAGE_WRITE(sxA, r0, al0);
    __syncthreads();            // A ready

    STAGE_LOAD(r1, 32);         // chunk1 loads in flight under COMPUTE(0)
    COMPUTE(0, sxA);
    STAGE_WRITE(sxB, r1, al1);  // different buffer: no barrier needed first
    __syncthreads();            // B ready

    COMPUTE(1, sxB);

    // ---- epilogue: store (64B-segment coalescing: 16 px x 4 co groups) ----
#pragma unroll
    for (int mt = 0; mt < 2; ++mt) {
        const int m0 = (m_half * 2 + mt) * 16;
#pragma unroll
        for (int h = 0; h < 2; ++h) {
            const int gy = gy0 + n_q;
            const int gx = gx0 + h * 16 + n_lane;
#pragma unroll
            for (int r = 0; r < 4; ++r) {
                const int co = m0 + q * 4 + r;
                out[(((size_t)b * CO_N + co) * HH + gy) * WW + gx] = acc[mt][h][r];
            }
        }
    }
#undef STAGE_LOAD
#undef STAGE_WRITE
#undef COMPUTE
}

extern "C" void kernel_launch(void* const* d_in, const int* in_sizes, int n_in,
                              void* d_out, int out_size, void* d_ws, size_t ws_size,
                              hipStream_t stream) {
    const float* x     = (const float*)d_in[0];
    const float* alpha = (const float*)d_in[1];
    const float* w     = (const float*)d_in[2];
    const float* bias  = (const float*)d_in[3];
    float* out  = (float*)d_out;
    ushort* wpk = (ushort*)d_ws;

    prepack_w<<<dim3((NFRAG + 255) / 256), dim3(256), 0, stream>>>(w, wpk);

    // 4096 blocks (8 per XCD-batch x 8 tx x 64 ty), XCD decode in-kernel
    conv_mfma<<<dim3(4096), dim3(512), 0, stream>>>(x, alpha, wpk, bias, out);
}